// Round 4
// baseline (534.166 us; speedup 1.0000x reference)
//
#include <hip/hip_runtime.h>
#include <math.h>

// MultiEmbodimentActionEncoder B=64,T=64,A=64,H=1024,C=16
// R8: maximum-boring register-direct GEMM. R5/R6/R7 all failed in the
// hand-built K-loop machinery (compiler drains around global_load_lds+ds_read;
// asm-by-ref outputs defeating SROA; a macro-rotated pipeline failing
// correctness). R8 keeps the two validated insights -- (1) no LDS / no
// barriers in the K-loop, (2) W streamed straight to registers -- and drops
// ALL manual pipelining and ALL inline asm. The K-loop is a pure
// load->pack->MFMA loop with no stores: the compiler is free to hoist
// next-step loads over MFMAs (unroll 2 widens its window), and 5 waves/CU
// (grid 32x40, single-wave blocks) overlap the remaining latency.
//  - single-wave blocks (64 thr): pairing sort done with wave ballots only;
//    zero LDS, zero __syncthreads in the whole kernel.
//  - wave tile M128xN32 (8 mt x 2 nt = 16 MFMA / K-step), pairs of batches
//    sharing a category => M=128 rows.
//  - tau fused into GEMM1 epilogue; bf16 pack via pk2 (RTNE, proven R4).

typedef short bf16x8 __attribute__((ext_vector_type(8)));
typedef float floatx4 __attribute__((ext_vector_type(4)));

__device__ inline short f2bf(float f) {
  union { float f; unsigned u; } v; v.f = f;
  unsigned u = v.u;
  return (short)(((u + 0x7fffu + ((u >> 16) & 1u)) >> 16) & 0xffffu);
}

// pack two fp32 -> two bf16 (RTNE) in one u32: lo=a, hi=b
__device__ __forceinline__ unsigned pk2(float a, float b) {
  union { float f; unsigned u; } x, y; x.f = a; y.f = b;
  unsigned ua = (x.u + 0x7fffu + ((x.u >> 16) & 1u)) >> 16;
  unsigned ub = (y.u + 0x7fffu + ((y.u >> 16) & 1u)) >> 16;
  return (ua & 0xffffu) | (ub << 16);
}

template<int K, bool A_F32, bool SWISH, bool OUT_BF16, bool TAU>
__global__ __launch_bounds__(64, 2) void gemm_kernel(
    const void* __restrict__ Aall, int lda,
    const float* __restrict__ Wall,   // (16, K, 1024)
    const float* __restrict__ bias,   // (16, 1024)
    const int* __restrict__ cat_ids,
    void* __restrict__ Out, int ldo,
    const int* __restrict__ ts)
{
  constexpr int NCOL = 1024;
  constexpr int KT = K / 32;
  (void)ts;

  const int lane = threadIdx.x;          // one wave per block
  const int quad = lane >> 4, l16 = lane & 15;

  // ---- category pairing, entirely in registers (wave ballots) ----
  const int myc = cat_ids[lane];         // lane == batch index
  int rank = 0, pst = 0, tot = 0;
  #pragma unroll
  for (int cc = 0; cc < 16; ++cc) {
    const unsigned long long m = __ballot(myc == cc);
    const int cnt = __popcll(m);
    const int pc  = 2 * ((cnt + 1) >> 1);       // pad count to even
    if (cc < myc)  pst += pc;
    if (cc == myc) rank = __popcll(m & ((1ull << lane) - 1ull));
    tot += pc;
  }
  const int slot = pst + rank;           // unique; pad slots are always odd
  const int e = blockIdx.y;
  if (e >= (tot >> 1)) return;           // uniform -> whole wave returns
  const unsigned long long m0 = __ballot(slot == 2 * e);
  const unsigned long long m1 = __ballot(slot == 2 * e + 1);
  const int b0v = __ffsll(m0) - 1;       // even slot always occupied
  const bool st1 = (m1 != 0ull);
  const int b1 = st1 ? (__ffsll(m1) - 1) : b0v;  // dummy: dup rows, mask store
  const int c = cat_ids[b0v];

  const int ns = blockIdx.x * 32;        // this wave's 32 output cols

  // A row offsets (elements): 8 x 16 rows = the full 128-row pair.
  int aoff[8];
  #pragma unroll
  for (int mt = 0; mt < 8; ++mt) {
    const int pr = mt * 16 + l16;
    const int batch = (pr < 64) ? b0v : b1;
    aoff[mt] = (batch * 64 + (pr & 63)) * lda;
  }

  // W base for this lane: W[c][k][ns + l16 (+16)]
  const float* wbase = Wall + (size_t)c * K * NCOL + ns + l16;

  floatx4 acc[8][2];
  #pragma unroll
  for (int mt = 0; mt < 8; ++mt) {
    acc[mt][0] = (floatx4){0.f, 0.f, 0.f, 0.f};
    acc[mt][1] = (floatx4){0.f, 0.f, 0.f, 0.f};
  }

  #pragma unroll 2
  for (int s = 0; s < KT; ++s) {
    const int k0 = s * 32 + quad * 8;

    float wv[16];
    #pragma unroll
    for (int j = 0; j < 8; ++j) {
      const float* wp = wbase + (size_t)(k0 + j) * NCOL;
      wv[j]     = wp[0];
      wv[8 + j] = wp[16];
    }
    union { bf16x8 v; unsigned u[4]; } w0, w1;
    #pragma unroll
    for (int j = 0; j < 4; ++j) {
      w0.u[j] = pk2(wv[2 * j],     wv[2 * j + 1]);
      w1.u[j] = pk2(wv[8 + 2 * j], wv[9 + 2 * j]);
    }

    bf16x8 av[8];
    #pragma unroll
    for (int mt = 0; mt < 8; ++mt) {
      if constexpr (A_F32) {
        const floatx4* p = (const floatx4*)((const float*)Aall + aoff[mt] + k0);
        const floatx4 x0 = p[0], x1 = p[1];
        union { bf16x8 v; unsigned u[4]; } t;
        t.u[0] = pk2(x0[0], x0[1]); t.u[1] = pk2(x0[2], x0[3]);
        t.u[2] = pk2(x1[0], x1[1]); t.u[3] = pk2(x1[2], x1[3]);
        av[mt] = t.v;
      } else {
        av[mt] = *(const bf16x8*)((const short*)Aall + aoff[mt] + k0);
      }
    }

    #pragma unroll
    for (int mt = 0; mt < 8; ++mt) {
      acc[mt][0] = __builtin_amdgcn_mfma_f32_16x16x32_bf16(
          av[mt], w0.v, acc[mt][0], 0, 0, 0);
      acc[mt][1] = __builtin_amdgcn_mfma_f32_16x16x32_bf16(
          av[mt], w1.v, acc[mt][1], 0, 0, 0);
    }
  }

  // Epilogue. C/D: row-in-tile = quad*4 + r, col-in-tile = l16.
  #pragma unroll
  for (int nt = 0; nt < 2; ++nt) {
    const int col = ns + nt * 16 + l16;
    const float bv = bias[(size_t)c * NCOL + col];
    #pragma unroll
    for (int mt = 0; mt < 8; ++mt) {
      const int prb = mt * 16 + quad * 4;
      const int batch = (prb < 64) ? b0v : b1;
      const bool do_store = (prb < 64) || st1;
      #pragma unroll
      for (int r = 0; r < 4; ++r) {
        const int row = batch * 64 + ((prb + r) & 63);
        float v = acc[mt][nt][r] + bv;
        if constexpr (SWISH) v = v / (1.f + __expf(-v));
        if (do_store) {
          if constexpr (OUT_BF16)
            ((short*)Out)[(size_t)row * ldo + col] = f2bf(v);
          else
            ((float*)Out)[(size_t)row * ldo + col] = v;
        }
      }
    }
  }

  // Fused tau: one 1024-vector per batch (timestep const across T),
  // broadcast into x's right half. This block covers cols ns..ns+31.
  if constexpr (TAU) {
    const float t0  = (float)ts[b0v];
    const float t1v = (float)ts[b1];
    const int ic = ns + (lane & 31);       // tau col in [0,1024)
    const int hi = ic & 511;
    const float ef = __expf(-(float)hi * 0.017988946039015980f); // ln(1e4)/512
    float v0, v1;
    if (ic < 512) { v0 = sinf(t0 * ef); v1 = sinf(t1v * ef); }
    else          { v0 = cosf(t0 * ef); v1 = cosf(t1v * ef); }
    const short q0 = f2bf(v0), q1 = f2bf(v1);
    short* xp = (short*)Out;
    const int r0 = lane >> 5;              // 2 lanes per col -> 64 rows
    #pragma unroll 4
    for (int rr = 0; rr < 32; ++rr) {
      const int rl = r0 + 2 * rr;
      xp[(size_t)(b0v * 64 + rl) * ldo + 1024 + ic] = q0;
      if (st1) xp[(size_t)(b1 * 64 + rl) * ldo + 1024 + ic] = q1;
    }
  }
}

extern "C" void kernel_launch(void* const* d_in, const int* in_sizes, int n_in,
                              void* d_out, int out_size, void* d_ws, size_t ws_size,
                              hipStream_t stream) {
  const float* actions   = (const float*)d_in[0];
  const int*   timesteps = (const int*)  d_in[1];
  const int*   cat_ids   = (const int*)  d_in[2];
  const float* W1 = (const float*)d_in[3];
  const float* B1 = (const float*)d_in[4];
  const float* W2 = (const float*)d_in[5];
  const float* B2 = (const float*)d_in[6];
  const float* W3 = (const float*)d_in[7];
  const float* B3 = (const float*)d_in[8];

  short* x = (short*)d_ws;                     // (4096, 2048) bf16 = 16 MiB
  short* h = x + (size_t)64 * 64 * 2048;       // (4096, 1024) bf16 =  8 MiB

  dim3 grid(32, 40), blk(64);

  // GEMM1 (K=64, fp32 A) + fused tau -> x
  gemm_kernel<64, true, false, true, true><<<grid, blk, 0, stream>>>(
      (const void*)actions, 64, W1, B1, cat_ids, (void*)x, 2048, timesteps);
  // GEMM2 (K=2048) + swish -> h
  gemm_kernel<2048, false, true, true, false><<<grid, blk, 0, stream>>>(
      (const void*)x, 2048, W2, B2, cat_ids, (void*)h, 1024, nullptr);
  // GEMM3 (K=1024) -> out (fp32)
  gemm_kernel<1024, false, false, false, false><<<grid, blk, 0, stream>>>(
      (const void*)h, 1024, W3, B3, cat_ids, d_out, 1024, nullptr);
}

// Round 5
// 364.571 us; speedup vs baseline: 1.4652x; 1.4652x over previous
//
#include <hip/hip_runtime.h>
#include <hip/hip_bf16.h>
#include <math.h>

// MultiEmbodimentActionEncoder B=64,T=64,A=64,H=1024,C=16
// R9 = R4 (best verified: 119us GEMM2) + split-K TLP.
// Root cause identified across R4-R8: grid never exceeded ~1.25 waves/SIMD,
// so every stall (R4 barrier drain, R8 serialized loads) was fully exposed.
// Hand-pipelining failed 4x (compiler drains / SROA defeat / spills).
// Fix: keep R4's proven LDS-staged kernel byte-for-byte, add blockIdx.z
// K-chunking (PARTIAL f32 epilogue, no bias), 4 blocks/CU resident ->
// inter-block overlap hides the per-tile drain (m114 mechanism).
// Partials summed by a small reduce kernel (bias + swish/pack there).
// Workspace tiers: nkz degrades to 1 (exact R4) if ws is small.

typedef short bf16x8 __attribute__((ext_vector_type(8)));
typedef float floatx4 __attribute__((ext_vector_type(4)));
typedef unsigned uintx2 __attribute__((ext_vector_type(2)));

__device__ inline short f2bf(float f) {
  union { float f; unsigned u; } v; v.f = f;
  unsigned u = v.u;
  return (short)(((u + 0x7fffu + ((u >> 16) & 1u)) >> 16) & 0xffffu);
}

// pack two fp32 -> two bf16 (RTNE) in one 32-bit word: lo=a, hi=b
__device__ inline unsigned pk2(float a, float b) {
  union { float f; unsigned u; } x, y; x.f = a; y.f = b;
  unsigned ua = (x.u + 0x7fffu + ((x.u >> 16) & 1u)) >> 16;
  unsigned ub = (y.u + 0x7fffu + ((y.u >> 16) & 1u)) >> 16;
  return (ua & 0xffffu) | (ub << 16);
}

#if __has_builtin(__builtin_amdgcn_global_load_lds)
__device__ inline void async16(float* lds, const float* g) {
  __builtin_amdgcn_global_load_lds(
      (const __attribute__((address_space(1))) unsigned int*)g,
      (__attribute__((address_space(3))) unsigned int*)lds, 16, 0, 0);
}
#define ASYNC_LDS 1
#else
__device__ inline void async16(float* lds, const float* g) {
  *(floatx4*)lds = *(const floatx4*)g;   // fallback: sync copy
}
#define ASYNC_LDS 0
#endif

// Stage 32(k) x 128(n) fp32 W tile into tilebuf with chunk swizzle:
// slot s (16B) holds W[k=s>>5][cols 4*cc..4*cc+3], cc = ((s&31) - 4*(k>>3))&31.
// Wsrc = W[c] + k0*1024 + ns ; row stride 1024 floats.
__device__ inline void stage_tile(float* tilebuf, const float* __restrict__ Wsrc,
                                  int tid) {
  const int wave = tid >> 6;
#if ASYNC_LDS
  #pragma unroll
  for (int i = 0; i < 4; ++i) {
    const int s  = i * 256 + tid;
    const int k  = s >> 5;
    const int p  = s & 31;
    const int cc = (p - 4 * (k >> 3)) & 31;
    const float* g = Wsrc + (size_t)k * 1024 + cc * 4;
    float* l = tilebuf + (size_t)(i * 256 + wave * 64) * 4;  // wave-uniform base
    async16(l, g);
  }
#else
  #pragma unroll
  for (int i = 0; i < 4; ++i) {
    const int s  = i * 256 + tid;
    const int k  = s >> 5;
    const int p  = s & 31;
    const int cc = (p - 4 * (k >> 3)) & 31;
    *(floatx4*)(tilebuf + (size_t)s * 4) =
        *(const floatx4*)(Wsrc + (size_t)k * 1024 + cc * 4);
  }
#endif
}

// Read B-frag (8 bf16: k = quad*8+j, fixed col) from swizzled fp32 tile.
__device__ inline bf16x8 read_bfrag(const float* __restrict__ tile, int col, int quad) {
  const int cc = col >> 2, c3 = col & 3;
  const int p  = (cc + 4 * quad) & 31;
  const float* base = tile + (size_t)p * 4 + c3 + (size_t)(quad * 8) * 128;
  float f[8];
  #pragma unroll
  for (int j = 0; j < 8; ++j) f[j] = base[(size_t)j * 128];
  union { bf16x8 v; unsigned u[4]; } r;
  #pragma unroll
  for (int j = 0; j < 4; ++j) r.u[j] = pk2(f[2 * j], f[2 * j + 1]);
  return r.v;
}

template<int K, bool A_F32, bool SWISH, bool OUT_BF16, bool PARTIAL>
__global__ __launch_bounds__(256) void gemm_kernel(
    const void* __restrict__ Aall, int lda,
    const float* __restrict__ Wall,   // (16, K, 1024)
    const float* __restrict__ bias,   // (16, 1024)
    const int* __restrict__ cat_ids,
    void* __restrict__ Out, int ldo)
{
  constexpr int N  = 1024;
  constexpr int KT = K / 32;
  __shared__ float wtile[2][32 * 128];     // 2 x 16 KiB
  __shared__ int s_b[80], s_c[80], s_np;

  const int tid = threadIdx.x;
  if (tid < 80) { s_b[tid] = -1; s_c[tid] = 0; }
  __syncthreads();
  if (tid < 64) {                          // wave 0: padded counting sort
    const int myc = cat_ids[tid];
    int rank = 0, pst = 0, tot = 0;
    #pragma unroll
    for (int c = 0; c < 16; ++c) {
      unsigned long long m = __ballot(myc == c);
      const int cnt = __popcll(m);
      const int pc  = 2 * ((cnt + 1) >> 1);  // pad to even
      if (c < myc)  pst += pc;
      if (c == myc) rank = __popcll(m & ((1ull << tid) - 1ull));
      tot += pc;
    }
    const int slot = pst + rank;
    s_b[slot] = tid;
    s_c[slot] = myc;
    if (tid == 0) s_np = tot >> 1;
  }
  __syncthreads();

  const int e = blockIdx.y;
  if (e >= s_np) return;                   // inactive pair slot
  const int b0v = s_b[2 * e];
  int b1 = s_b[2 * e + 1];
  const int c = s_c[2 * e];
  const bool st1 = (b1 >= 0);
  if (!st1) b1 = b0v;                      // dummy: duplicate, mask store

  const int wave = tid >> 6, lane = tid & 63;
  const int quad = lane >> 4, l16 = lane & 15;
  const int wm = wave >> 1, wn = wave & 1; // 2x2 wave grid: M64 x N64 each
  const int ns = blockIdx.x * 128;
  const float* Wc = Wall + (size_t)c * K * N + ns;

  // split-K: this block covers k-tiles [kt0, kt1)
  const int ktc = KT / (int)gridDim.z;
  const int kt0 = (int)blockIdx.z * ktc;
  const int kt1 = kt0 + ktc;

  const char* arow[4];
  #pragma unroll
  for (int mt = 0; mt < 4; ++mt) {
    const int pr = wm * 64 + mt * 16 + l16;        // 0..127
    const int batch = (pr < 64) ? b0v : b1;
    const int row = batch * 64 + (pr & 63);
    arow[mt] = (const char*)Aall + (size_t)row * lda * (A_F32 ? 4 : 2);
  }

  floatx4 acc[4][4];
  #pragma unroll
  for (int mt = 0; mt < 4; ++mt)
    #pragma unroll
    for (int nt = 0; nt < 4; ++nt)
      acc[mt][nt] = (floatx4){0.f, 0.f, 0.f, 0.f};

  stage_tile(&wtile[0][0], Wc + (size_t)kt0 * 32 * 1024, tid);
  int buf = 0;
  for (int kt = kt0; kt < kt1; ++kt) {
    __syncthreads();                       // vmcnt(0) drain -> wtile[buf] ready
    if (kt + 1 < kt1)
      stage_tile(&wtile[buf ^ 1][0], Wc + (size_t)(kt + 1) * 32 * 1024, tid);

    const float* tp = &wtile[buf][0];
    const int kk = kt * 32 + quad * 8;

    bf16x8 af[4];
    #pragma unroll
    for (int mt = 0; mt < 4; ++mt) {
      if constexpr (A_F32) {
        const floatx4* p = (const floatx4*)(arow[mt] + (size_t)kk * 4);
        floatx4 x0 = p[0], x1 = p[1];
        union { bf16x8 v; unsigned u[4]; } t;
        t.u[0] = pk2(x0[0], x0[1]); t.u[1] = pk2(x0[2], x0[3]);
        t.u[2] = pk2(x1[0], x1[1]); t.u[3] = pk2(x1[2], x1[3]);
        af[mt] = t.v;
      } else {
        af[mt] = *(const bf16x8*)(arow[mt] + (size_t)kk * 2);
      }
    }

    #pragma unroll
    for (int nt = 0; nt < 4; ++nt) {
      bf16x8 bf = read_bfrag(tp, wn * 64 + nt * 16 + l16, quad);
      #pragma unroll
      for (int mt = 0; mt < 4; ++mt)
        acc[mt][nt] = __builtin_amdgcn_mfma_f32_16x16x32_bf16(af[mt], bf, acc[mt][nt], 0, 0, 0);
    }
    buf ^= 1;
  }

  // Epilogue. C/D: row = quad*4 + r, col = l16 (within 16x16 tile).
  if constexpr (PARTIAL) {
    // raw f32 partial, no bias/activation; chunk z at stride 4096*1024
    float* P = (float*)Out + (size_t)blockIdx.z * (4096ull * 1024);
    #pragma unroll
    for (int nt = 0; nt < 4; ++nt) {
      const int col = ns + wn * 64 + nt * 16 + l16;
      #pragma unroll
      for (int mt = 0; mt < 4; ++mt) {
        const int prb = wm * 64 + mt * 16 + quad * 4;
        const int batch = (prb < 64) ? b0v : b1;
        const bool do_store = (prb < 64) || st1;
        #pragma unroll
        for (int r = 0; r < 4; ++r) {
          const int row = batch * 64 + ((prb + r) & 63);
          if (do_store) P[(size_t)row * ldo + col] = acc[mt][nt][r];
        }
      }
    }
  } else {
    #pragma unroll
    for (int nt = 0; nt < 4; ++nt) {
      const int col = ns + wn * 64 + nt * 16 + l16;
      const float bv = bias[(size_t)c * N + col];
      #pragma unroll
      for (int mt = 0; mt < 4; ++mt) {
        const int prb = wm * 64 + mt * 16 + quad * 4;
        const int batch = (prb < 64) ? b0v : b1;
        const bool do_store = (prb < 64) || st1;
        #pragma unroll
        for (int r = 0; r < 4; ++r) {
          const int row = batch * 64 + ((prb + r) & 63);
          float v = acc[mt][nt][r] + bv;
          if constexpr (SWISH) v = v / (1.f + __expf(-v));
          if (do_store) {
            if constexpr (OUT_BF16)
              ((short*)Out)[(size_t)row * ldo + col] = f2bf(v);
            else
              ((float*)Out)[(size_t)row * ldo + col] = v;
          }
        }
      }
    }
  }
}

// Sum nchunk f32 partials (each 4096x1024), add per-category bias, optional
// swish, store bf16 or f32. One float4 per thread.
template<bool SWISH, bool OUT_BF16>
__global__ __launch_bounds__(256) void reduce_kernel(
    const float* __restrict__ P, int nchunk,
    const float* __restrict__ bias, const int* __restrict__ cat_ids,
    void* __restrict__ Out, int ldo)
{
  const size_t base = ((size_t)blockIdx.x * 256 + threadIdx.x) * 4;
  const int row = (int)(base >> 10);
  const int col = (int)(base & 1023);
  floatx4 s = *(const floatx4*)(P + base);
  for (int z = 1; z < nchunk; ++z)
    s += *(const floatx4*)(P + (size_t)z * (4096ull * 1024) + base);
  const int c = cat_ids[row >> 6];
  const floatx4 bv = *(const floatx4*)(bias + (size_t)c * 1024 + col);
  float v[4];
  #pragma unroll
  for (int j = 0; j < 4; ++j) {
    v[j] = s[j] + bv[j];
    if constexpr (SWISH) v[j] = v[j] / (1.f + __expf(-v[j]));
  }
  if constexpr (OUT_BF16) {
    uintx2 o; o[0] = pk2(v[0], v[1]); o[1] = pk2(v[2], v[3]);
    *(uintx2*)((short*)Out + (size_t)row * ldo + col) = o;
  } else {
    floatx4 o = (floatx4){v[0], v[1], v[2], v[3]};
    *(floatx4*)((float*)Out + (size_t)row * ldo + col) = o;
  }
}

// tau: per batch one 1024-vector (timestep constant across T) broadcast to the
// right half of x (row stride 2048 bf16).
__global__ __launch_bounds__(256) void tau_kernel(const int* __restrict__ ts,
                                                  short* __restrict__ x)
{
  const int b = blockIdx.x;
  const float t = (float)ts[b];
  const int tid = threadIdx.x;
  #pragma unroll
  for (int q = 0; q < 4; ++q) {
    const int i  = q * 256 + tid;
    const int hi = i & 511;
    const float e = __expf(-(float)hi * 0.017988946039015980f);  // ln(1e4)/512
    const float freq = t * e;
    const float v = (i < 512) ? sinf(freq) : cosf(freq);
    const short sv = f2bf(v);
    short* base = x + (size_t)(b * 64) * 2048 + 1024 + i;
    #pragma unroll 4
    for (int tt = 0; tt < 64; ++tt) base[(size_t)tt * 2048] = sv;
  }
}

extern "C" void kernel_launch(void* const* d_in, const int* in_sizes, int n_in,
                              void* d_out, int out_size, void* d_ws, size_t ws_size,
                              hipStream_t stream) {
  const float* actions   = (const float*)d_in[0];
  const int*   timesteps = (const int*)  d_in[1];
  const int*   cat_ids   = (const int*)  d_in[2];
  const float* W1 = (const float*)d_in[3];
  const float* B1 = (const float*)d_in[4];
  const float* W2 = (const float*)d_in[5];
  const float* B2 = (const float*)d_in[6];
  const float* W3 = (const float*)d_in[7];
  const float* B3 = (const float*)d_in[8];

  short* x = (short*)d_ws;                     // (4096, 2048) bf16 = 16 MiB
  short* h = x + (size_t)64 * 64 * 2048;       // (4096, 1024) bf16 =  8 MiB
  float* pbuf = (float*)(h + (size_t)64 * 64 * 1024);  // partials after 24 MiB

  const size_t CH = 4096ull * 1024 * 4;        // one partial chunk = 16 MiB
  const size_t used = 24ull * 1024 * 1024;
  const size_t avail = (ws_size > used) ? (ws_size - used) : 0;
  int nkz2 = 1, nkz3 = 1;
  if      (avail >= 8 * CH) { nkz2 = 4; nkz3 = 4; }
  else if (avail >= 6 * CH) { nkz2 = 4; nkz3 = 2; }
  else if (avail >= 4 * CH) { nkz2 = 2; nkz3 = 2; }
  else if (avail >= 2 * CH) { nkz2 = 2; nkz3 = 1; }
  float* p2 = pbuf;
  float* p3 = pbuf + (size_t)nkz2 * (CH / 4);

  dim3 blk(256);

  // GEMM1 (K=64, fp32 A) -> x left half (bias, bf16), + tau -> x right half
  gemm_kernel<64, true, false, true, false><<<dim3(8, 40, 1), blk, 0, stream>>>(
      (const void*)actions, 64, W1, B1, cat_ids, (void*)x, 2048);
  tau_kernel<<<64, 256, 0, stream>>>(timesteps, x);

  // GEMM2 (K=2048) + swish -> h
  if (nkz2 > 1) {
    gemm_kernel<2048, false, false, false, true><<<dim3(8, 40, nkz2), blk, 0, stream>>>(
        (const void*)x, 2048, W2, nullptr, cat_ids, (void*)p2, 1024);
    reduce_kernel<true, true><<<4096, 256, 0, stream>>>(
        p2, nkz2, B2, cat_ids, (void*)h, 1024);
  } else {
    gemm_kernel<2048, false, true, true, false><<<dim3(8, 40, 1), blk, 0, stream>>>(
        (const void*)x, 2048, W2, B2, cat_ids, (void*)h, 1024);
  }

  // GEMM3 (K=1024) -> out (fp32)
  if (nkz3 > 1) {
    gemm_kernel<1024, false, false, false, true><<<dim3(8, 40, nkz3), blk, 0, stream>>>(
        (const void*)h, 1024, W3, nullptr, cat_ids, (void*)p3, 1024);
    reduce_kernel<false, false><<<4096, 256, 0, stream>>>(
        p3, nkz3, B3, cat_ids, d_out, 1024);
  } else {
    gemm_kernel<1024, false, false, false, false><<<dim3(8, 40, 1), blk, 0, stream>>>(
        (const void*)h, 1024, W3, B3, cat_ids, d_out, 1024);
  }
}